// Round 8
// baseline (762.189 us; speedup 1.0000x reference)
//
#include <hip/hip_runtime.h>
#include <stdint.h>

// dims fixed by the reference
#define TT 512
#define BB 1024
#define SS 64
#define HH 128
#define TBR (TT*BB)
#define NTILE (TBR/16)     // 32768 16-row MFMA tiles, tile(t,bx) = t*64+bx
#define MW_TPW 16          // tiles per wave in k_mlp
#define MGRID (NTILE/MW_TPW)   // 2048 single-wave blocks

typedef __attribute__((ext_vector_type(8))) short short8;    // 8 x bf16
typedef __attribute__((ext_vector_type(4))) float floatx4;   // MFMA acc
typedef unsigned short u16;
typedef unsigned int u32;
typedef struct { u32 x, y; } u32x2;

__device__ __forceinline__ float bf2f(u16 u){union{u32 i;float f;}v;v.i=((u32)u)<<16;return v.f;}
__device__ __forceinline__ u16 f2bf(float f){union{float f;u32 i;}v;v.f=f;u32 r=v.i+0x7FFFu+((v.i>>16)&1u);return (u16)(r>>16);}
__device__ __forceinline__ float frcp(float x){ return __builtin_amdgcn_rcpf(x); }

// Deterministic dtype detector (R3-proven).
__device__ __forceinline__ bool buf_is_bf16(const u16* p) {
  int ok = 0;
#pragma unroll
  for (int i = 0; i < 32; ++i) {
    u32 v = p[2*i] & 0x7FFFu;
    u32 e = v >> 7;
    ok += (v == 0u || (e >= 96u && e <= 128u)) ? 1 : 0;
  }
  return ok >= 24;
}

template<bool BF> __device__ __forceinline__ float ld1(const void* p, size_t i){
  if constexpr (BF) return bf2f(((const u16*)p)[i]);
  else              return ((const float*)p)[i];
}
__device__ __forceinline__ short8 pack8(floatx4 a, floatx4 b){
  short8 r;
  r[0]=(short)f2bf(a[0]); r[1]=(short)f2bf(a[1]); r[2]=(short)f2bf(a[2]); r[3]=(short)f2bf(a[3]);
  r[4]=(short)f2bf(b[0]); r[5]=(short)f2bf(b[1]); r[6]=(short)f2bf(b[2]); r[7]=(short)f2bf(b[3]);
  return r;
}
template<bool BF> __device__ __forceinline__ short8 ld8(const void* p, size_t i){
  if constexpr (BF) return *(const short8*)((const u16*)p + i);
  else {
    const float* f = (const float*)p + i;
    return pack8(*(const floatx4*)f, *(const floatx4*)(f + 4));
  }
}
template<bool BF> __device__ __forceinline__ void st1(void* p, size_t i, float v){
  if constexpr (BF) ((u16*)p)[i] = f2bf(v);
  else              ((float*)p)[i] = v;
}

// LDS-only barrier (R4-proven): lgkmcnt(0)+s_barrier, no vmcnt drain.
__device__ __forceinline__ void barrier_lds() {
  __asm__ __volatile__("" ::: "memory");
  __builtin_amdgcn_s_waitcnt(0xC07F);
  __builtin_amdgcn_s_barrier();
  __asm__ __volatile__("" ::: "memory");
}

// A-fragment-ordered LDS index for v_mfma_f32_16x16x32_bf16 (R3/R4-proven).
__device__ __forceinline__ int fragidx(int m,int k){
  return ((k>>5)<<9)+((m+(((k>>3)&3)<<4))<<3)+(k&7);
}
__device__ __forceinline__ floatx4 mfma(short8 a, short8 b, floatx4 c){
  return __builtin_amdgcn_mfma_f32_16x16x32_bf16(a,b,c,0,0,0);
}

// ---------------------------------------------------------------------------
// K1 body (R12): batch MLP, single-wave blocks, ALL weights in registers.
// W1 B-frags (64 VGPR) + W2 B-frags (128 VGPR) in regs -> zero LDS weight
// reads (R10 spent ~380cyc/tile/wave on W2 LDS reads). Per-wave 4KB LDS
// scratch only for the C-frag->A-frag transposes (same-wave RAW, lgkmcnt
// only, no barriers anywhere). 2048 blocks x 1 wave x 16 tiles = NTILE.
// Identical op order / rounding to R10.
// ---------------------------------------------------------------------------
template<bool BF>
__device__ __forceinline__ void mlp_u_body(
    const void* __restrict__ x,
    const void* __restrict__ W1, const void* __restrict__ b1,
    const void* __restrict__ W2, const void* __restrict__ b2,
    u16* __restrict__ h2g, u16* S)
{
  const int lane = threadIdx.x & 63;
  const int n16 = lane & 15, q = lane >> 4;

  short8 w1b[8][2], w2b[8][4];
  float b1v[8], b2v[8];
#pragma unroll
  for (int j = 0; j < 8; ++j) {
    int row = 16*j + n16;
#pragma unroll
    for (int ks = 0; ks < 2; ++ks) w1b[j][ks] = ld8<BF>(W1, (size_t)row*SS + ks*32 + q*8);
#pragma unroll
    for (int ks = 0; ks < 4; ++ks) w2b[j][ks] = ld8<BF>(W2, (size_t)row*HH + ks*32 + q*8);
    b1v[j] = ld1<BF>(b1, row);
    b2v[j] = ld1<BF>(b2, row);
  }

  const int tile0 = blockIdx.x * MW_TPW;

  // 1-deep x prefetch in the BF path (named regs; fp32 path loads at use)
  short8 xb0, xb1;
  if constexpr (BF) {
    size_t base = ((size_t)tile0*16 + n16)*SS + q*8;
    xb0 = *(const short8*)((const u16*)x + base);
    xb1 = *(const short8*)((const u16*)x + base + 32);
  }

  for (int i = 0; i < MW_TPW; ++i) {
    const int tau = tile0 + i;
    short8 xc0, xc1;
    if constexpr (BF) {
      xc0 = xb0; xc1 = xb1;
      if (i + 1 < MW_TPW) {
        size_t base = ((size_t)(tau+1)*16 + n16)*SS + q*8;
        xb0 = *(const short8*)((const u16*)x + base);
        xb1 = *(const short8*)((const u16*)x + base + 32);
      }
    } else {
      const float* f = (const float*)x + ((size_t)tau*16 + n16)*SS + q*8;
      xc0 = pack8(*(const floatx4*)f, *(const floatx4*)(f+4));
      xc1 = pack8(*(const floatx4*)(f+32), *(const floatx4*)(f+36));
    }
    // ---- layer 1: h1 = relu(W1@x+b1), C-frag -> scratch ----------------
#pragma unroll
    for (int j = 0; j < 8; ++j) {
      floatx4 a = {0.f,0.f,0.f,0.f};
      a = mfma(xc0, w1b[j][0], a);
      a = mfma(xc1, w1b[j][1], a);
#pragma unroll
      for (int r = 0; r < 4; ++r) {
        float v = a[r] + b1v[j]; v = v > 0.f ? v : 0.f;
        S[fragidx(4*q + r, 16*j + n16)] = f2bf(v);
      }
    }
    // ---- h1 A-frags (same-wave RAW: compiler inserts lgkmcnt) ----------
    short8 h1a0 = *(const short8*)(S + 0*512 + lane*8);
    short8 h1a1 = *(const short8*)(S + 1*512 + lane*8);
    short8 h1a2 = *(const short8*)(S + 2*512 + lane*8);
    short8 h1a3 = *(const short8*)(S + 3*512 + lane*8);
    // ---- layer 2: h2 = relu(W2@h1+b2) -> scratch (W2 from REGS) --------
#pragma unroll
    for (int j = 0; j < 8; ++j) {
      floatx4 a = {0.f,0.f,0.f,0.f};
      a = mfma(h1a0, w2b[j][0], a);
      a = mfma(h1a1, w2b[j][1], a);
      a = mfma(h1a2, w2b[j][2], a);
      a = mfma(h1a3, w2b[j][3], a);
#pragma unroll
      for (int r = 0; r < 4; ++r) {
        float v = a[r] + b2v[j]; v = v > 0.f ? v : 0.f;
        S[fragidx(4*q + r, 16*j + n16)] = f2bf(v);
      }
    }
    // ---- dump tile (A-frag order), 64 B/lane coalesced -----------------
    {
      const u16* src = S + lane*32;
      u16* dst = h2g + (size_t)tau*2048 + lane*32;
      short8 d0 = *(const short8*)(src);
      short8 d1 = *(const short8*)(src + 8);
      short8 d2 = *(const short8*)(src + 16);
      short8 d3 = *(const short8*)(src + 24);
      *(short8*)(dst)      = d0;
      *(short8*)(dst + 8)  = d1;
      *(short8*)(dst + 16) = d2;
      *(short8*)(dst + 24) = d3;
    }
  }
}

__global__ __launch_bounds__(64, 2) void k_mlp_u(
    const void* __restrict__ x,
    const void* __restrict__ W1, const void* __restrict__ b1,
    const void* __restrict__ W2, const void* __restrict__ b2,
    u16* __restrict__ h2g)
{
  __shared__ __align__(16) u16 S[2048];
  if (buf_is_bf16((const u16*)W1)) mlp_u_body<true >(x, W1, b1, W2, b2, h2g, S);
  else                             mlp_u_body<false>(x, W1, b1, W2, b2, h2g, S);
}

// ---------------------------------------------------------------------------
// K2 body (R12): R6-proven scan + (a) gate biases folded into stage3 MFMA
// C-init (tr = fma(s4,agh,pipe) etc: -3 VALU/row/step), (b) pipeA/pipeB
// ping-pong (no 12-mov rotate). Structure, barriers, LDS identical to the
// 495us kernel.
// ---------------------------------------------------------------------------
template<bool BF>
__device__ __forceinline__ void scan_body(
    const void* __restrict__ done_, const void* __restrict__ gstate,
    const void* __restrict__ Wih, const void* __restrict__ bih,
    const void* __restrict__ Whh, const void* __restrict__ bhh,
    const void* __restrict__ Wa, const void* __restrict__ ba,
    const void* __restrict__ Wc, const void* __restrict__ bc,
    const u16* __restrict__ h2g,
    float* __restrict__ lgws, float* __restrict__ vws,
    void* __restrict__ out, int bx, u16 (*hbuf)[2048])
{
  const int tid = threadIdx.x, lane = tid & 63, wv = tid >> 6;
  const int n16 = lane & 15, q = lane >> 4;
  const int b0 = bx * 16;
  const int jj = 16*wv + n16;

  // ---- weights -> register B-fragments ---------------------------------
  short8 wif[3][4], whf[3][4], scf[4];
  float bihv2, bhv2, bb0, bb1;
  {
    float bi0, bi1, bh0, bh1;
#pragma unroll
    for (int g = 0; g < 3; ++g) {
      int grow = g*128 + jj;
#pragma unroll
      for (int ks = 0; ks < 4; ++ks) {
        wif[g][ks] = ld8<BF>(Wih, (size_t)grow*HH + ks*32 + q*8);
        whf[g][ks] = ld8<BF>(Whh, (size_t)grow*HH + ks*32 + q*8);
      }
      float bi = ld1<BF>(bih, grow), bh = ld1<BF>(bhh, grow);
      if (g == 0) { bi0 = bi; bh0 = bh; }
      else if (g == 1) { bi1 = bi; bh1 = bh; }
      else { bihv2 = bi; bhv2 = bh; }
    }
    bb0 = bi0 + bh0;
    bb1 = bi1 + bh1;
  }
  if (wv == 1) {
#pragma unroll
    for (int ks = 0; ks < 4; ++ks) scf[ks] = ld8<BF>(Wa, (size_t)n16*HH + ks*32 + q*8);
  } else if (wv == 2) {
#pragma unroll
    for (int ks = 0; ks < 4; ++ks) {
      short8 z = {0,0,0,0,0,0,0,0};
      if (n16 == 0) z = ld8<BF>(Wc, (size_t)ks*32 + q*8);
      scf[ks] = z;
    }
  } else {
#pragma unroll
    for (int ks = 0; ks < 4; ++ks) { short8 z = {0,0,0,0,0,0,0,0}; scf[ks] = z; }
  }
  const float bav = ld1<BF>(ba, n16);
  const float bcv = ld1<BF>(bc, 0);
  const float ginit[3] = {bb0, bb1, bihv2};    // stage3 C-inits (bias-fold)

  // ---- h0 state --------------------------------------------------------
  float hreg[4];
#pragma unroll
  for (int r = 0; r < 4; ++r) {
    hreg[r] = ld1<BF>(gstate, (size_t)(b0 + 4*q + r)*HH + jj);
    hbuf[0][fragidx(4*q + r, jj)] = f2bf(hreg[r]);
  }
  float s4cur[2][4];
#pragma unroll
  for (int s = 0; s < 2; ++s)
#pragma unroll
    for (int r = 0; r < 4; ++r)
      s4cur[s][r] = 1.f - ld1<BF>(done_, (size_t)s*BB + b0 + 4*q + r);
  u32x2 draw[2];  floatx4 fdraw[2];
#pragma unroll
  for (int s = 0; s < 2; ++s) { draw[s].x = draw[s].y = 0; fdraw[s] = floatx4{0,0,0,0}; }

  // ---- h2 frag prefetch (named double buffer) --------------------------
  const u16* const hz = h2g + (size_t)bx*2048;      // tile(t) = t*64 + bx
  short8 h2p0[4], h2p1[4];
#pragma unroll
  for (int ks = 0; ks < 4; ++ks)
    h2p0[ks] = *(const short8*)(hz + (size_t)0*64*2048 + ks*512 + lane*8);
#pragma unroll
  for (int ks = 0; ks < 4; ++ks)
    h2p1[ks] = *(const short8*)(hz + (size_t)1*64*2048 + ks*512 + lane*8);
  floatx4 pipeA[3], pipeB[3];
#pragma unroll
  for (int g = 0; g < 3; ++g) {            // stage3(tile 0) -> pipeA for rec(0)
    float gv = ginit[g];
    floatx4 a = {gv, gv, gv, gv};
#pragma unroll
    for (int ks = 0; ks < 4; ++ks) a = mfma(h2p0[ks], wif[g][ks], a);
    pipeA[g] = a;
  }
#pragma unroll
  for (int ks = 0; ks < 4; ++ks)           // tile 2 into buffer 0
    h2p0[ks] = *(const short8*)(hz + (size_t)2*64*2048 + ks*512 + lane*8);
  __syncthreads();

  u16* hw0 = &hbuf[1][0] + fragidx(4*q, jj);   // even step writes hbuf[1]
  u16* hw1 = &hbuf[0][0] + fragidx(4*q, jj);   // odd  step writes hbuf[0]

  auto step = [&](int t, const u16* hb_rd, u16* hw, floatx4 (&pin)[3],
                  floatx4 (&pout)[3], short8 (&hp)[4], float (&s4r)[4],
                  bool dopf) {
    // 1) critical h reads first
    short8 haf[4];
#pragma unroll
    for (int ks = 0; ks < 4; ++ks)
      haf[ks] = *(const short8*)(hb_rd + ks*512 + lane*8);

    // 2) stage3: gx(tile t+1) from hp -> pout (bias in C-init)
#pragma unroll
    for (int g = 0; g < 3; ++g) {
      float gv = ginit[g];
      floatx4 a = {gv, gv, gv, gv};
#pragma unroll
      for (int ks = 0; ks < 4; ++ks) a = mfma(hp[ks], wif[g][ks], a);
      pout[g] = a;
    }
    // 3) refill: tile t+3 (clamped; tail redundant, never consumed)
    {
      const int tl = (t+3 < TT) ? t+3 : TT-1;
      const u16* tp = hz + (size_t)tl*64*2048;
#pragma unroll
      for (int ks = 0; ks < 4; ++ks)
        hp[ks] = *(const short8*)(tp + ks*512 + lane*8);
    }

    // 4) head for t-1 (fire-and-forget)
    if (t > 0 && (wv == 1 || wv == 2)) {
      floatx4 a = {0.f,0.f,0.f,0.f};
#pragma unroll
      for (int ks = 0; ks < 4; ++ks) a = mfma(haf[ks], scf[ks], a);
      if (wv == 1) {
#pragma unroll
        for (int r = 0; r < 4; ++r)
          lgws[((size_t)(t-1)*BB + b0 + 4*q + r)*16 + n16] = a[r] + bav;
      } else if (n16 == 0) {
#pragma unroll
        for (int r = 0; r < 4; ++r)
          vws[(size_t)(t-1)*BB + b0 + 4*q + r] = a[r] + bcv;
      }
    }

    // 5) recurrence step t
    floatx4 agh[3];
#pragma unroll
    for (int g = 0; g < 3; ++g) {
      floatx4 a = {0.f,0.f,0.f,0.f};
#pragma unroll
      for (int ks = 0; ks < 4; ++ks) a = mfma(haf[ks], whf[g][ks], a);
      agh[g] = a;
    }
#pragma unroll
    for (int r = 0; r < 4; ++r) {
      float s4 = s4r[r];
      float tr = __builtin_fmaf(s4, agh[0][r], pin[0][r]);   // biases folded
      float tz = __builtin_fmaf(s4, agh[1][r], pin[1][r]);
      float xn_ = pin[2][r];
      float hn_ = __builtin_fmaf(s4, agh[2][r], bhv2);
      float rg = frcp(1.f + __expf(-tr));
      float zg = frcp(1.f + __expf(-tz));
      float ni = __builtin_fmaf(rg, hn_, xn_);
      float ng = __builtin_fmaf(2.f, frcp(1.f + __expf(-2.f*ni)), -1.f);  // tanh
      float hold = hreg[r] * s4;
      float hnew = __builtin_fmaf(zg, hold - ng, ng);
      hreg[r] = hnew;
      hw[r*8] = f2bf(hnew);
    }

    // 6) done prefetch (once per 2 steps; clamped at tail)
    if (dopf) {
#pragma unroll
      for (int ss = 0; ss < 2; ++ss) {
        const int tl = (t+2+ss < TT) ? t+2+ss : TT-1;
        size_t didx = (size_t)tl*BB + b0 + 4*q;
        if constexpr (BF) draw[ss] = *(const u32x2*)((const u16*)done_ + didx);
        else              fdraw[ss] = *(const floatx4*)((const float*)done_ + didx);
      }
    }

    barrier_lds();                        // the ONE barrier per step
  };

  for (int t0 = 0; t0 < TT; t0 += 2) {
    step(t0,     &hbuf[0][0], hw0, pipeA, pipeB, h2p1, s4cur[0], true);
    step(t0 + 1, &hbuf[1][0], hw1, pipeB, pipeA, h2p0, s4cur[1], false);
    // rotate done regs (tail values unused)
    if constexpr (BF) {
#pragma unroll
      for (int ss = 0; ss < 2; ++ss) {
        s4cur[ss][0] = 1.f - bf2f((u16)(draw[ss].x & 0xFFFF));
        s4cur[ss][1] = 1.f - bf2f((u16)(draw[ss].x >> 16));
        s4cur[ss][2] = 1.f - bf2f((u16)(draw[ss].y & 0xFFFF));
        s4cur[ss][3] = 1.f - bf2f((u16)(draw[ss].y >> 16));
      }
    } else {
#pragma unroll
      for (int ss = 0; ss < 2; ++ss)
#pragma unroll
        for (int r = 0; r < 4; ++r) s4cur[ss][r] = 1.f - fdraw[ss][r];
    }
  }

  // epilogue: head for t=511 (h_511 in hbuf[0]) + h_last output
  {
    if (wv == 1 || wv == 2) {
      short8 haf[4];
#pragma unroll
      for (int ks = 0; ks < 4; ++ks) haf[ks] = *(const short8*)(&hbuf[0][0] + ks*512 + lane*8);
      floatx4 a = {0.f,0.f,0.f,0.f};
#pragma unroll
      for (int ks = 0; ks < 4; ++ks) a = mfma(haf[ks], scf[ks], a);
      if (wv == 1) {
#pragma unroll
        for (int r = 0; r < 4; ++r)
          lgws[((size_t)(TT-1)*BB + b0 + 4*q + r)*16 + n16] = a[r] + bav;
      } else if (n16 == 0) {
#pragma unroll
        for (int r = 0; r < 4; ++r)
          vws[(size_t)(TT-1)*BB + b0 + 4*q + r] = a[r] + bcv;
      }
    }
#pragma unroll
    for (int r = 0; r < 4; ++r)
      st1<BF>(out, (size_t)3*TBR + (size_t)(b0 + 4*q + r)*HH + jj, hreg[r]);
  }
}

__global__ __launch_bounds__(512, 2) void k_scan_u(
    const void* __restrict__ done_, const void* __restrict__ gstate,
    const void* __restrict__ Wih, const void* __restrict__ bih,
    const void* __restrict__ Whh, const void* __restrict__ bhh,
    const void* __restrict__ Wa, const void* __restrict__ ba,
    const void* __restrict__ Wc, const void* __restrict__ bc,
    const void* __restrict__ W1,
    const u16* __restrict__ h2g,
    float* __restrict__ lgws, float* __restrict__ vws,
    void* __restrict__ out)
{
  __shared__ __align__(16) u16 hbuf[2][2048];
  if (buf_is_bf16((const u16*)W1))
    scan_body<true >(done_, gstate, Wih, bih, Whh, bhh, Wa, ba, Wc, bc,
                     h2g, lgws, vws, out, blockIdx.x, hbuf);
  else
    scan_body<false>(done_, gstate, Wih, bih, Whh, bhh, Wa, ba, Wc, bc,
                     h2g, lgws, vws, out, blockIdx.x, hbuf);
}

// ---------------------------------------------------------------------------
// Deep fallback (R5 mono, twins) if workspace can't hold h2g. UNCHANGED.
// ---------------------------------------------------------------------------
struct TrueT  { static constexpr bool value = true;  };
struct FalseT { static constexpr bool value = false; };

template<bool BF>
__global__ __launch_bounds__(512, 2) void k_scan_mono(
    const void* __restrict__ x, const void* __restrict__ done_,
    const void* __restrict__ gstate,
    const void* __restrict__ W1, const void* __restrict__ b1,
    const void* __restrict__ W2, const void* __restrict__ b2,
    const void* __restrict__ Wih, const void* __restrict__ bih,
    const void* __restrict__ Whh, const void* __restrict__ bhh,
    const void* __restrict__ Wa, const void* __restrict__ ba,
    const void* __restrict__ Wc, const void* __restrict__ bc,
    float* __restrict__ lgws, float* __restrict__ vws,
    void* __restrict__ out)
{
  if (buf_is_bf16((const u16*)W1) != BF) return;

  const int tid = threadIdx.x, lane = tid & 63, wv = tid >> 6;
  const int n16 = lane & 15, q = lane >> 4;
  const int b0 = blockIdx.x * 16;
  const int jj = 16*wv + n16;

  __shared__ __align__(16) u16 hbuf[2][2048];
  __shared__ __align__(16) u16 h1f[2][2048];
  __shared__ __align__(16) u16 h2f[2][2048];

  short8 w1f[2], w2f[4], wif[3][4], whf[3][4], scf[4];
  float b1v, b2v, bihv2, bhv2, bb0, bb1;
  {
    int row = wv*16 + n16;
#pragma unroll
    for (int ks = 0; ks < 2; ++ks) w1f[ks] = ld8<BF>(W1, (size_t)row*SS + ks*32 + q*8);
    b1v = ld1<BF>(b1, row);
#pragma unroll
    for (int ks = 0; ks < 4; ++ks) w2f[ks] = ld8<BF>(W2, (size_t)row*HH + ks*32 + q*8);
    b2v = ld1<BF>(b2, row);
    float bi0, bi1, bh0, bh1;
#pragma unroll
    for (int g = 0; g < 3; ++g) {
      int grow = g*128 + jj;
#pragma unroll
      for (int ks = 0; ks < 4; ++ks) {
        wif[g][ks] = ld8<BF>(Wih, (size_t)grow*HH + ks*32 + q*8);
        whf[g][ks] = ld8<BF>(Whh, (size_t)grow*HH + ks*32 + q*8);
      }
      float bi = ld1<BF>(bih, grow), bh = ld1<BF>(bhh, grow);
      if (g == 0) { bi0 = bi; bh0 = bh; }
      else if (g == 1) { bi1 = bi; bh1 = bh; }
      else { bihv2 = bi; bhv2 = bh; }
    }
    bb0 = bi0 + bh0;
    bb1 = bi1 + bh1;
  }
  if (wv == 1) {
#pragma unroll
    for (int ks = 0; ks < 4; ++ks) scf[ks] = ld8<BF>(Wa, (size_t)n16*HH + ks*32 + q*8);
  } else if (wv == 2) {
#pragma unroll
    for (int ks = 0; ks < 4; ++ks) {
      short8 z = {0,0,0,0,0,0,0,0};
      if (n16 == 0) z = ld8<BF>(Wc, (size_t)ks*32 + q*8);
      scf[ks] = z;
    }
  } else {
#pragma unroll
    for (int ks = 0; ks < 4; ++ks) { short8 z = {0,0,0,0,0,0,0,0}; scf[ks] = z; }
  }
  const float bav = ld1<BF>(ba, n16);
  const float bcv = ld1<BF>(bc, 0);

  float hreg[4];
#pragma unroll
  for (int r = 0; r < 4; ++r) {
    hreg[r] = ld1<BF>(gstate, (size_t)(b0 + 4*q + r)*HH + jj);
    hbuf[0][fragidx(4*q + r, jj)] = f2bf(hreg[r]);
  }
  short8 xc[2][2], xn[2][2];
#pragma unroll
  for (int s = 0; s < 2; ++s)
#pragma unroll
    for (int ks = 0; ks < 2; ++ks)
      xc[s][ks] = ld8<BF>(x, ((size_t)s*BB + b0 + n16)*SS + ks*32 + q*8);
  float s4cur[2][4];
#pragma unroll
  for (int s = 0; s < 2; ++s)
#pragma unroll
    for (int r = 0; r < 4; ++r) s4cur[s][r] = 1.f;
  u32x2 draw[2];  floatx4 fdraw[2];
#pragma unroll
  for (int s = 0; s < 2; ++s) { draw[s].x = draw[s].y = 0; fdraw[s] = floatx4{0,0,0,0}; }
#pragma unroll
  for (int s = 0; s < 2; ++s)
#pragma unroll
    for (int ks = 0; ks < 2; ++ks) { short8 z={0,0,0,0,0,0,0,0}; xn[s][ks]=z; }
  floatx4 pipe[2][3];
#pragma unroll
  for (int s = 0; s < 2; ++s)
#pragma unroll
    for (int g = 0; g < 3; ++g) pipe[s][g] = floatx4{0.f,0.f,0.f,0.f};
  __syncthreads();

  u16* hw0 = &hbuf[1][0] + fragidx(4*q, jj);
  u16* hw1 = &hbuf[0][0] + fragidx(4*q, jj);

  auto iter = [&](int t0, auto steady) {
    constexpr bool ST = decltype(steady)::value;
#pragma unroll
    for (int s = 0; s < 2; ++s) {
      const int t = t0 + s;
      const bool s1on = ST || (t <= TT-5);
      const bool s2on = ST || (t >= -3 && t <= TT-4);
      const bool s3on = ST || (t >= -2 && t <= TT-3);
      const bool ron  = ST || (t >= 0);
      const int pw = t & 1;

      short8 haf[4];
      if (ron) {
#pragma unroll
        for (int ks = 0; ks < 4; ++ks)
          haf[ks] = *(const short8*)(&hbuf[pw][0] + ks*512 + lane*8);
      }
      if (s1on) {
        floatx4 a = {0.f,0.f,0.f,0.f};
        a = mfma(xc[s][0], w1f[0], a);
        a = mfma(xc[s][1], w1f[1], a);
#pragma unroll
        for (int r = 0; r < 4; ++r) {
          float v = a[r] + b1v; v = v > 0.f ? v : 0.f;
          h1f[pw][fragidx(4*q + r, jj)] = f2bf(v);
        }
      }
      if (s2on) {
        short8 h1a[4];
#pragma unroll
        for (int ks = 0; ks < 4; ++ks)
          h1a[ks] = *(const short8*)(&h1f[pw^1][0] + ks*512 + lane*8);
        floatx4 a = {0.f,0.f,0.f,0.f};
#pragma unroll
        for (int ks = 0; ks < 4; ++ks) a = mfma(h1a[ks], w2f[ks], a);
#pragma unroll
        for (int r = 0; r < 4; ++r) {
          float v = a[r] + b2v; v = v > 0.f ? v : 0.f;
          h2f[pw][fragidx(4*q + r, jj)] = f2bf(v);
        }
      }
      if (s == 0) {
        if (ST || (t0 + 6 < TT)) {
          if constexpr (BF) {
#pragma unroll
            for (int ss = 0; ss < 2; ++ss) {
              size_t base = ((size_t)(t0+6+ss)*BB + b0 + n16)*SS + q*8;
              xn[ss][0] = *(const short8*)((const u16*)x + base);
              xn[ss][1] = *(const short8*)((const u16*)x + base + 32);
            }
          }
        }
        if (ST || (t0+2 >= 0 && t0+2 < TT)) {
#pragma unroll
          for (int ss = 0; ss < 2; ++ss) {
            size_t didx = (size_t)(t0+2+ss)*BB + b0 + 4*q;
            if constexpr (BF) draw[ss] = *(const u32x2*)((const u16*)done_ + didx);
            else              fdraw[ss] = *(const floatx4*)((const float*)done_ + didx);
          }
        }
      }
      if (ron) {
        if (t > 0 && (wv == 1 || wv == 2)) {
          floatx4 a = {0.f,0.f,0.f,0.f};
#pragma unroll
          for (int ks = 0; ks < 4; ++ks) a = mfma(haf[ks], scf[ks], a);
          if (wv == 1) {
#pragma unroll
            for (int r = 0; r < 4; ++r)
              lgws[((size_t)(t-1)*BB + b0 + 4*q + r)*16 + n16] = a[r] + bav;
          } else if (n16 == 0) {
#pragma unroll
            for (int r = 0; r < 4; ++r)
              vws[(size_t)(t-1)*BB + b0 + 4*q + r] = a[r] + bcv;
          }
        }
        floatx4 agh[3];
#pragma unroll
        for (int g = 0; g < 3; ++g) {
          floatx4 a = {0.f,0.f,0.f,0.f};
#pragma unroll
          for (int ks = 0; ks < 4; ++ks) a = mfma(haf[ks], whf[g][ks], a);
          agh[g] = a;
        }
        u16* hw = pw ? hw1 : hw0;
#pragma unroll
        for (int r = 0; r < 4; ++r) {
          float s4 = s4cur[s][r];
          float tr = pipe[s][0][r] + __builtin_fmaf(s4, agh[0][r], bb0);
          float tz = pipe[s][1][r] + __builtin_fmaf(s4, agh[1][r], bb1);
          float xn_ = pipe[s][2][r] + bihv2;
          float hn_ = __builtin_fmaf(s4, agh[2][r], bhv2);
          float rg = frcp(1.f + __expf(-tr));
          float zg = frcp(1.f + __expf(-tz));
          float ni = __builtin_fmaf(rg, hn_, xn_);
          float ng = __builtin_fmaf(2.f, frcp(1.f + __expf(-2.f*ni)), -1.f);
          float hold = hreg[r] * s4;
          float hnew = __builtin_fmaf(zg, hold - ng, ng);
          hreg[r] = hnew;
          hw[r*8] = f2bf(hnew);
        }
      }
      if (s3on) {
        short8 h2a[4];
#pragma unroll
        for (int ks = 0; ks < 4; ++ks)
          h2a[ks] = *(const short8*)(&h2f[pw^1][0] + ks*512 + lane*8);
#pragma unroll
        for (int g = 0; g < 3; ++g) {
          floatx4 a = {0.f,0.f,0.f,0.f};
#pragma unroll
          for (int ks = 0; ks < 4; ++ks) a = mfma(h2a[ks], wif[g][ks], a);
          pipe[s][g] = a;
        }
      }
      barrier_lds();
    }
    if (ST || (t0 + 6 < TT)) {
      if constexpr (BF) {
#pragma unroll
        for (int ss = 0; ss < 2; ++ss) { xc[ss][0] = xn[ss][0]; xc[ss][1] = xn[ss][1]; }
      } else {
#pragma unroll
        for (int ss = 0; ss < 2; ++ss) {
          size_t base = ((size_t)(t0+6+ss)*BB + b0 + n16)*SS + q*8;
          xc[ss][0] = ld8<false>(x, base);
          xc[ss][1] = ld8<false>(x, base + 32);
        }
      }
    }
    if (ST || (t0+2 >= 0 && t0+2 < TT)) {
      if constexpr (BF) {
#pragma unroll
        for (int ss = 0; ss < 2; ++ss) {
          s4cur[ss][0] = 1.f - bf2f((u16)(draw[ss].x & 0xFFFF));
          s4cur[ss][1] = 1.f - bf2f((u16)(draw[ss].x >> 16));
          s4cur[ss][2] = 1.f - bf2f((u16)(draw[ss].y & 0xFFFF));
          s4cur[ss][3] = 1.f - bf2f((u16)(draw[ss].y >> 16));
        }
      } else {
#pragma unroll
        for (int ss = 0; ss < 2; ++ss)
#pragma unroll
          for (int r = 0; r < 4; ++r) s4cur[ss][r] = 1.f - fdraw[ss][r];
      }
    }
  };

  iter(-4, FalseT{});
  iter(-2, FalseT{});
  for (int t0 = 0; t0 <= TT - 8; t0 += 2) iter(t0, TrueT{});
  iter(TT-6, FalseT{});
  iter(TT-4, FalseT{});
  iter(TT-2, FalseT{});

  {
    if (wv == 1 || wv == 2) {
      short8 haf[4];
#pragma unroll
      for (int ks = 0; ks < 4; ++ks) haf[ks] = *(const short8*)(&hbuf[0][0] + ks*512 + lane*8);
      floatx4 a = {0.f,0.f,0.f,0.f};
#pragma unroll
      for (int ks = 0; ks < 4; ++ks) a = mfma(haf[ks], scf[ks], a);
      if (wv == 1) {
#pragma unroll
        for (int r = 0; r < 4; ++r)
          lgws[((size_t)(TT-1)*BB + b0 + 4*q + r)*16 + n16] = a[r] + bav;
      } else if (n16 == 0) {
#pragma unroll
        for (int r = 0; r < 4; ++r)
          vws[(size_t)(TT-1)*BB + b0 + 4*q + r] = a[r] + bcv;
      }
    }
#pragma unroll
    for (int r = 0; r < 4; ++r)
      st1<BF>(out, (size_t)3*TBR + (size_t)(b0 + 4*q + r)*HH + jj, hreg[r]);
  }
}

// ---------------------------------------------------------------------------
// K3 (R12): head finisher, dtype twins MERGED (branch only at the stores).
// ---------------------------------------------------------------------------
__global__ __launch_bounds__(256) void k_head_u(
    const float* __restrict__ lgws, const float* __restrict__ vws,
    const int* __restrict__ action, const void* __restrict__ W1,
    void* __restrict__ out)
{
  const bool bf = buf_is_bf16((const u16*)W1);
  size_t row = (size_t)blockIdx.x * 256 + threadIdx.x;
  if (row >= (size_t)TBR) return;
  const float* lp = lgws + row*16;
  floatx4 v[4];
#pragma unroll
  for (int i = 0; i < 4; ++i) v[i] = *(const floatx4*)(lp + 4*i);
  float mx = v[0][0];
#pragma unroll
  for (int i = 0; i < 4; ++i)
#pragma unroll
    for (int j = 0; j < 4; ++j) mx = fmaxf(mx, v[i][j]);
  float sum = 0.f, se = 0.f;
#pragma unroll
  for (int i = 0; i < 4; ++i)
#pragma unroll
    for (int j = 0; j < 4; ++j) {
      float d = v[i][j] - mx;
      float e = __expf(d);
      sum += e; se = __builtin_fmaf(e, d, se);
    }
  float ls = __logf(sum);
  int a = action[row];
  float la = lp[a];
  float lpa = (la - mx) - ls;
  float ent = ls - se * frcp(sum);
  float val = vws[row];
  if (bf) {
    st1<true>(out, row*3,     lpa);
    st1<true>(out, row*3 + 1, ent);
    st1<true>(out, row*3 + 2, val);
  } else {
    st1<false>(out, row*3,     lpa);
    st1<false>(out, row*3 + 1, ent);
    st1<false>(out, row*3 + 2, val);
  }
}

// ---------------------------------------------------------------------------
extern "C" void kernel_launch(void* const* d_in, const int* in_sizes, int n_in,
                              void* d_out, int out_size, void* d_ws, size_t ws_size,
                              hipStream_t stream) {
  const void* x    = d_in[0];
  const void* done = d_in[1];
  const int*  act  = (const int*)d_in[2];
  const void* gst  = d_in[3];
  const void* W1   = d_in[4];
  const void* b1   = d_in[5];
  const void* W2   = d_in[6];
  const void* b2   = d_in[7];
  const void* Wih  = d_in[8];
  const void* bih  = d_in[9];
  const void* Whh  = d_in[10];
  const void* bhh  = d_in[11];
  const void* Wa   = d_in[12];
  const void* ba   = d_in[13];
  const void* Wc   = d_in[14];
  const void* bc   = d_in[15];

  float* lgws = (float*)d_ws;                       // [TBR,16] fp32 = 33.6 MB
  float* vws  = lgws + (size_t)16*TBR;              // [TBR]    fp32 =  2.1 MB
  u16*   h2g  = (u16*)(vws + (size_t)TBR);          // [NTILE,2048] bf16 frag = 134 MB
  const size_t need = (size_t)(16*TBR + TBR)*4 + (size_t)NTILE*4096;

  if (ws_size >= need) {
    hipLaunchKernelGGL(k_mlp_u, dim3(MGRID), dim3(64), 0, stream,
                       x, W1, b1, W2, b2, h2g);
    hipLaunchKernelGGL(k_scan_u, dim3(64), dim3(512), 0, stream,
                       done, gst, Wih, bih, Whh, bhh, Wa, ba, Wc, bc,
                       W1, h2g, lgws, vws, d_out);
  } else {
    hipLaunchKernelGGL((k_scan_mono<true>),  dim3(64), dim3(512), 0, stream,
                       x, done, gst, W1, b1, W2, b2, Wih, bih,
                       Whh, bhh, Wa, ba, Wc, bc, lgws, vws, d_out);
    hipLaunchKernelGGL((k_scan_mono<false>), dim3(64), dim3(512), 0, stream,
                       x, done, gst, W1, b1, W2, b2, Wih, bih,
                       Whh, bhh, Wa, ba, Wc, bc, lgws, vws, d_out);
  }
  hipLaunchKernelGGL(k_head_u, dim3(TBR/256), dim3(256), 0, stream,
                     lgws, vws, act, W1, d_out);
}